// Round 6
// baseline (501.484 us; speedup 1.0000x reference)
//
#include <hip/hip_runtime.h>

// ExternalNeighbors: per-pair displacement + periodic shift + cutoff mask.
// Outputs (concatenated flat, all float32):
//   [0N..1N) dist | [1N..2N) pair_first | [2N..3N) pair_second
//   [3N..6N) paircoord (N,3) | [6N..7N) mask
//
// Round-5 evidence: NT loads raised FETCH 110->133MB (threw away L3-warm
// inputs); NT stores amplified WRITE +6.5% but still net-positive.
// Round-6: plain loads (reclaim L3 hits) + NT stores only + 8 pairs/thread
// (2KB contiguous wave-bursts per output stream, 16 gathers in flight).

typedef float f32x4 __attribute__((ext_vector_type(4)));
typedef int   i32x4 __attribute__((ext_vector_type(4)));

#define HARD_DIST_CUTOFF 2.0f

__global__ __launch_bounds__(256) void build_gather_table(
    const float* __restrict__ coords,      // n_real * 3
    const int*   __restrict__ real_atoms,  // n_real
    f32x4* __restrict__ tab,               // n_real (padded xyz_)
    int n_real)
{
    const int i = blockIdx.x * blockDim.x + threadIdx.x;
    if (i < n_real) {
        const int a = real_atoms[i];
        const float* c = coords + 3 * (size_t)a;
        f32x4 v;
        v.x = c[0]; v.y = c[1]; v.z = c[2]; v.w = 0.0f;
        tab[i] = v;  // plain store: keep table L2-resident for the gathers
    }
}

__global__ __launch_bounds__(256) void external_neighbors_v5(
    const f32x4* __restrict__ tab,          // n_real pre-gathered coords
    const int*   __restrict__ shifts,       // n_pairs * 3
    const float* __restrict__ cell,         // 9
    const int*   __restrict__ pair_first,   // n_pairs
    const int*   __restrict__ pair_second,  // n_pairs
    float* __restrict__ out,
    int n_pairs)
{
    const float c00 = cell[0], c01 = cell[1], c02 = cell[2];
    const float c10 = cell[3], c11 = cell[4], c12 = cell[5];
    const float c20 = cell[6], c21 = cell[7], c22 = cell[8];

    const size_t N = (size_t)n_pairs;
    float* __restrict__ out_dist = out;
    float* __restrict__ out_pf   = out + N;
    float* __restrict__ out_ps   = out + 2 * N;
    float* __restrict__ out_pc   = out + 3 * N;
    float* __restrict__ out_mask = out + 6 * N;

    const int tid    = blockIdx.x * blockDim.x + threadIdx.x;
    const int nthr   = gridDim.x * blockDim.x;
    const int nbatch = n_pairs >> 3;  // batches of 8 pairs

    for (int b = tid; b < nbatch; b += nthr) {
        const int base = b << 3;

        // ---- plain (cached) stream loads: inputs are L3-warm ----
        const i32x4* pfp4 = reinterpret_cast<const i32x4*>(pair_first  + base);
        const i32x4* psp4 = reinterpret_cast<const i32x4*>(pair_second + base);
        const i32x4 pfA = pfp4[0], pfB = pfp4[1];
        const i32x4 psA = psp4[0], psB = psp4[1];
        const i32x4* sh = reinterpret_cast<const i32x4*>(shifts + 3 * (size_t)base);
        const i32x4 sA = sh[0], sB = sh[1], sC = sh[2];
        const i32x4 sD = sh[3], sE = sh[4], sF = sh[5];

        const int pf[8] = {pfA.x, pfA.y, pfA.z, pfA.w, pfB.x, pfB.y, pfB.z, pfB.w};
        const int ps[8] = {psA.x, psA.y, psA.z, psA.w, psB.x, psB.y, psB.z, psB.w};
        const int s0[8] = {sA.x, sA.w, sB.z, sC.y, sD.x, sD.w, sE.z, sF.y};
        const int s1[8] = {sA.y, sB.x, sB.w, sC.z, sD.y, sE.x, sE.w, sF.z};
        const int s2[8] = {sA.z, sB.y, sC.x, sC.w, sD.z, sE.y, sF.x, sF.w};

        // ---- 16 independent 16B gathers (L2/L3-resident table) ----
        f32x4 A[8], B[8];
        #pragma unroll
        for (int k = 0; k < 8; ++k) A[k] = tab[pf[k]];
        #pragma unroll
        for (int k = 0; k < 8; ++k) B[k] = tab[ps[k]];

        // ---- compute ----
        float dv[8], pfv[8], psv[8], mv[8];
        float dxv[8], dyv[8], dzv[8];
        #pragma unroll
        for (int k = 0; k < 8; ++k) {
            const float f0 = (float)s0[k], f1 = (float)s1[k], f2 = (float)s2[k];
            const float dx = B[k].x - A[k].x + f0 * c00 + f1 * c10 + f2 * c20;
            const float dy = B[k].y - A[k].y + f0 * c01 + f1 * c11 + f2 * c21;
            const float dz = B[k].z - A[k].z + f0 * c02 + f1 * c12 + f2 * c22;
            const float d  = sqrtf(dx * dx + dy * dy + dz * dz);
            const bool  m  = d < HARD_DIST_CUTOFF;
            dv[k]  = m ? d : 0.0f;
            pfv[k] = m ? (float)pf[k] : -1.0f;
            psv[k] = m ? (float)ps[k] : -1.0f;
            mv[k]  = m ? 1.0f : 0.0f;
            dxv[k] = m ? dx : 0.0f;
            dyv[k] = m ? dy : 0.0f;
            dzv[k] = m ? dz : 0.0f;
        }

        // ---- nontemporal stores: 32B/thread per stream (2KB wave bursts) ----
        #pragma unroll
        for (int h = 0; h < 2; ++h) {
            const int o = 4 * h;
            const f32x4 dq  = {dv[o],  dv[o+1],  dv[o+2],  dv[o+3]};
            const f32x4 pq  = {pfv[o], pfv[o+1], pfv[o+2], pfv[o+3]};
            const f32x4 sq  = {psv[o], psv[o+1], psv[o+2], psv[o+3]};
            const f32x4 mq  = {mv[o],  mv[o+1],  mv[o+2],  mv[o+3]};
            __builtin_nontemporal_store(dq, reinterpret_cast<f32x4*>(out_dist + base) + h);
            __builtin_nontemporal_store(pq, reinterpret_cast<f32x4*>(out_pf   + base) + h);
            __builtin_nontemporal_store(sq, reinterpret_cast<f32x4*>(out_ps   + base) + h);
            __builtin_nontemporal_store(mq, reinterpret_cast<f32x4*>(out_mask + base) + h);
        }
        f32x4* pc = reinterpret_cast<f32x4*>(out_pc + 3 * (size_t)base);
        const f32x4 p0 = {dxv[0], dyv[0], dzv[0], dxv[1]};
        const f32x4 p1 = {dyv[1], dzv[1], dxv[2], dyv[2]};
        const f32x4 p2 = {dzv[2], dxv[3], dyv[3], dzv[3]};
        const f32x4 p3 = {dxv[4], dyv[4], dzv[4], dxv[5]};
        const f32x4 p4 = {dyv[5], dzv[5], dxv[6], dyv[6]};
        const f32x4 p5 = {dzv[6], dxv[7], dyv[7], dzv[7]};
        __builtin_nontemporal_store(p0, pc + 0);
        __builtin_nontemporal_store(p1, pc + 1);
        __builtin_nontemporal_store(p2, pc + 2);
        __builtin_nontemporal_store(p3, pc + 3);
        __builtin_nontemporal_store(p4, pc + 4);
        __builtin_nontemporal_store(p5, pc + 5);
    }

    // tail (n_pairs % 8 != 0): scalar fallback
    for (int p = (nbatch << 3) + tid; p < n_pairs; p += nthr) {
        const int pfs = pair_first[p];
        const int pss = pair_second[p];
        const float f0 = (float)shifts[3 * p + 0];
        const float f1 = (float)shifts[3 * p + 1];
        const float f2 = (float)shifts[3 * p + 2];
        const f32x4 Aa = tab[pfs];
        const f32x4 Bb = tab[pss];
        const float dx = Bb.x - Aa.x + f0 * c00 + f1 * c10 + f2 * c20;
        const float dy = Bb.y - Aa.y + f0 * c01 + f1 * c11 + f2 * c21;
        const float dz = Bb.z - Aa.z + f0 * c02 + f1 * c12 + f2 * c22;
        const float d  = sqrtf(dx * dx + dy * dy + dz * dz);
        const bool  m  = d < HARD_DIST_CUTOFF;
        out_dist[p] = m ? d : 0.0f;
        out_pf[p]   = m ? (float)pfs : -1.0f;
        out_ps[p]   = m ? (float)pss : -1.0f;
        out_pc[3*(size_t)p+0] = m ? dx : 0.0f;
        out_pc[3*(size_t)p+1] = m ? dy : 0.0f;
        out_pc[3*(size_t)p+2] = m ? dz : 0.0f;
        out_mask[p] = m ? 1.0f : 0.0f;
    }
}

// Fallback (ws too small): two-hop scalar kernel.
__global__ __launch_bounds__(256) void external_neighbors_v2(
    const float* __restrict__ coords,
    const int*   __restrict__ real_atoms,
    const int*   __restrict__ shifts,
    const float* __restrict__ cell,
    const int*   __restrict__ pair_first,
    const int*   __restrict__ pair_second,
    float* __restrict__ out,
    int n_pairs)
{
    const float c00 = cell[0], c01 = cell[1], c02 = cell[2];
    const float c10 = cell[3], c11 = cell[4], c12 = cell[5];
    const float c20 = cell[6], c21 = cell[7], c22 = cell[8];
    const size_t N = (size_t)n_pairs;
    float* out_dist = out;
    float* out_pf   = out + N;
    float* out_ps   = out + 2 * N;
    float* out_pc   = out + 3 * N;
    float* out_mask = out + 6 * N;
    const int tid = blockIdx.x * blockDim.x + threadIdx.x;
    const int stride = gridDim.x * blockDim.x;
    for (int p = tid; p < n_pairs; p += stride) {
        const int pfs = pair_first[p];
        const int pss = pair_second[p];
        const float f0 = (float)shifts[3 * p + 0];
        const float f1 = (float)shifts[3 * p + 1];
        const float f2 = (float)shifts[3 * p + 2];
        const int iaa = real_atoms[pfs];
        const int ibb = real_atoms[pss];
        const float dx = coords[3*ibb+0] - coords[3*iaa+0] + f0*c00 + f1*c10 + f2*c20;
        const float dy = coords[3*ibb+1] - coords[3*iaa+1] + f0*c01 + f1*c11 + f2*c21;
        const float dz = coords[3*ibb+2] - coords[3*iaa+2] + f0*c02 + f1*c12 + f2*c22;
        const float d  = sqrtf(dx*dx + dy*dy + dz*dz);
        const bool  m  = d < HARD_DIST_CUTOFF;
        out_dist[p] = m ? d : 0.0f;
        out_pf[p]   = m ? (float)pfs : -1.0f;
        out_ps[p]   = m ? (float)pss : -1.0f;
        out_pc[3*(size_t)p+0] = m ? dx : 0.0f;
        out_pc[3*(size_t)p+1] = m ? dy : 0.0f;
        out_pc[3*(size_t)p+2] = m ? dz : 0.0f;
        out_mask[p] = m ? 1.0f : 0.0f;
    }
}

extern "C" void kernel_launch(void* const* d_in, const int* in_sizes, int n_in,
                              void* d_out, int out_size, void* d_ws, size_t ws_size,
                              hipStream_t stream) {
    const float* coords      = (const float*)d_in[0];  // (128,1024,3) f32
    const int*   real_atoms  = (const int*)d_in[1];    // (131072,) int
    const int*   shifts      = (const int*)d_in[2];    // (8388608,3) int
    const float* cell        = (const float*)d_in[3];  // (3,3) f32
    const int*   pair_first  = (const int*)d_in[4];    // (8388608,) int
    const int*   pair_second = (const int*)d_in[5];    // (8388608,) int
    float*       out         = (float*)d_out;

    const int n_real  = in_sizes[1];  // 131072
    const int n_pairs = in_sizes[4];  // 8388608

    const size_t tab_bytes = (size_t)n_real * sizeof(f32x4);

    if (ws_size >= tab_bytes) {
        f32x4* tab = (f32x4*)d_ws;
        build_gather_table<<<(n_real + 255) / 256, 256, 0, stream>>>(
            coords, real_atoms, tab, n_real);

        // 8 pairs/thread: 1,048,576 threads -> 4096 blocks, single pass
        const int nbatch = n_pairs >> 3;
        const int grid   = (nbatch + 255) / 256;
        external_neighbors_v5<<<grid, 256, 0, stream>>>(
            tab, shifts, cell, pair_first, pair_second, out, n_pairs);
    } else {
        external_neighbors_v2<<<2048, 256, 0, stream>>>(
            coords, real_atoms, shifts, cell, pair_first, pair_second, out, n_pairs);
    }
}

// Round 7
// 404.768 us; speedup vs baseline: 1.2389x; 1.2389x over previous
//
#include <hip/hip_runtime.h>

// ExternalNeighbors: per-pair displacement + periodic shift + cutoff mask.
// Outputs (concatenated flat, all float32):
//   [0N..1N) dist | [1N..2N) pair_first | [2N..3N) pair_second
//   [3N..6N) paircoord (N,3) | [6N..7N) mask
//
// Ledger: v2 231us (4x ILP) -> v3 181us (1-hop float4 gather table)
//   -> v4 169us (NT ld+st; FETCH rose 110->133, WRITE 229->244)
//   -> v5 251us REGRESS (8pr/thr NT stores = partial-line, WRITE 460MB;
//      plain loads good: FETCH 91MB)
// v6: 4 pairs/thread + plain loads + NT stores, paircoord staged through
// LDS so every NT store instruction is a contiguous 1KB full-line burst.

typedef float f32x4 __attribute__((ext_vector_type(4)));
typedef int   i32x4 __attribute__((ext_vector_type(4)));

#define HARD_DIST_CUTOFF 2.0f

__global__ __launch_bounds__(256) void build_gather_table(
    const float* __restrict__ coords,      // n_real * 3
    const int*   __restrict__ real_atoms,  // n_real
    f32x4* __restrict__ tab,               // n_real (padded xyz_)
    int n_real)
{
    const int i = blockIdx.x * blockDim.x + threadIdx.x;
    if (i < n_real) {
        const int a = real_atoms[i];
        const float* c = coords + 3 * (size_t)a;
        f32x4 v;
        v.x = c[0]; v.y = c[1]; v.z = c[2]; v.w = 0.0f;
        tab[i] = v;  // plain store: keep table cache-resident for the gathers
    }
}

// Requires n_pairs % 1024 == 0 and grid*256*4 == n_pairs (exact, no tail).
__global__ __launch_bounds__(256) void external_neighbors_v6(
    const f32x4* __restrict__ tab,          // n_real pre-gathered coords
    const int*   __restrict__ shifts,       // n_pairs * 3
    const float* __restrict__ cell,         // 9
    const int*   __restrict__ pair_first,   // n_pairs
    const int*   __restrict__ pair_second,  // n_pairs
    float* __restrict__ out,
    int n_pairs)
{
    __shared__ float lds_pc[4][768];  // per-wave 3KB staging for paircoord

    const float c00 = cell[0], c01 = cell[1], c02 = cell[2];
    const float c10 = cell[3], c11 = cell[4], c12 = cell[5];
    const float c20 = cell[6], c21 = cell[7], c22 = cell[8];

    const size_t N = (size_t)n_pairs;
    float* __restrict__ out_dist = out;
    float* __restrict__ out_pf   = out + N;
    float* __restrict__ out_ps   = out + 2 * N;
    float* __restrict__ out_pc   = out + 3 * N;
    float* __restrict__ out_mask = out + 6 * N;

    const int tid  = blockIdx.x * blockDim.x + threadIdx.x;
    const int base = tid << 2;                 // 4 pairs/thread
    const int wv   = threadIdx.x >> 6;         // wave within block
    const int lane = threadIdx.x & 63;

    // ---- plain (cached) stream loads: inputs are L3-warm ----
    const i32x4 pf4 = *reinterpret_cast<const i32x4*>(pair_first  + base);
    const i32x4 ps4 = *reinterpret_cast<const i32x4*>(pair_second + base);
    const i32x4* sh = reinterpret_cast<const i32x4*>(shifts + 3 * (size_t)base);
    const i32x4 sA = sh[0], sB = sh[1], sC = sh[2];

    const int pf[4] = {pf4.x, pf4.y, pf4.z, pf4.w};
    const int ps[4] = {ps4.x, ps4.y, ps4.z, ps4.w};
    const int s0[4] = {sA.x, sA.w, sB.z, sC.y};
    const int s1[4] = {sA.y, sB.x, sB.w, sC.z};
    const int s2[4] = {sA.z, sB.y, sC.x, sC.w};

    // ---- 8 independent 16B gathers (cache-resident table) ----
    f32x4 A[4], B[4];
    #pragma unroll
    for (int k = 0; k < 4; ++k) A[k] = tab[pf[k]];
    #pragma unroll
    for (int k = 0; k < 4; ++k) B[k] = tab[ps[k]];

    // ---- compute ----
    f32x4 dist, pfo, pso, msk;
    float dxv[4], dyv[4], dzv[4];
    #pragma unroll
    for (int k = 0; k < 4; ++k) {
        const float f0 = (float)s0[k], f1 = (float)s1[k], f2 = (float)s2[k];
        const float dx = B[k].x - A[k].x + f0 * c00 + f1 * c10 + f2 * c20;
        const float dy = B[k].y - A[k].y + f0 * c01 + f1 * c11 + f2 * c21;
        const float dz = B[k].z - A[k].z + f0 * c02 + f1 * c12 + f2 * c22;
        const float d  = sqrtf(dx * dx + dy * dy + dz * dz);
        const bool  m  = d < HARD_DIST_CUTOFF;
        dist[k] = m ? d : 0.0f;
        pfo[k]  = m ? (float)pf[k] : -1.0f;
        pso[k]  = m ? (float)ps[k] : -1.0f;
        msk[k]  = m ? 1.0f : 0.0f;
        dxv[k]  = m ? dx : 0.0f;
        dyv[k]  = m ? dy : 0.0f;
        dzv[k]  = m ? dz : 0.0f;
    }

    // ---- stage paircoord in LDS (3 x b128 writes, 48B stride) ----
    f32x4* myl = reinterpret_cast<f32x4*>(&lds_pc[wv][12 * lane]);
    myl[0] = (f32x4){dxv[0], dyv[0], dzv[0], dxv[1]};
    myl[1] = (f32x4){dyv[1], dzv[1], dxv[2], dyv[2]};
    myl[2] = (f32x4){dzv[2], dxv[3], dyv[3], dzv[3]};
    __syncthreads();

    // ---- NT stores: every instruction a contiguous 1KB wave burst ----
    __builtin_nontemporal_store(dist, reinterpret_cast<f32x4*>(out_dist + base));
    __builtin_nontemporal_store(pfo,  reinterpret_cast<f32x4*>(out_pf   + base));
    __builtin_nontemporal_store(pso,  reinterpret_cast<f32x4*>(out_ps   + base));
    __builtin_nontemporal_store(msk,  reinterpret_cast<f32x4*>(out_mask + base));

    // paircoord: wave-contiguous from LDS (3KB per wave, 3 x 1KB bursts)
    float* pcw = out_pc + 768 * (size_t)((blockIdx.x << 2) + wv);
    #pragma unroll
    for (int h = 0; h < 3; ++h) {
        const f32x4 v = *reinterpret_cast<const f32x4*>(&lds_pc[wv][256 * h + 4 * lane]);
        __builtin_nontemporal_store(v, reinterpret_cast<f32x4*>(pcw + 256 * h + 4 * lane));
    }
}

// Generic fallback (any n_pairs; also used if ws too small for the table):
__global__ __launch_bounds__(256) void external_neighbors_v2(
    const float* __restrict__ coords,
    const int*   __restrict__ real_atoms,
    const int*   __restrict__ shifts,
    const float* __restrict__ cell,
    const int*   __restrict__ pair_first,
    const int*   __restrict__ pair_second,
    float* __restrict__ out,
    int n_pairs)
{
    const float c00 = cell[0], c01 = cell[1], c02 = cell[2];
    const float c10 = cell[3], c11 = cell[4], c12 = cell[5];
    const float c20 = cell[6], c21 = cell[7], c22 = cell[8];
    const size_t N = (size_t)n_pairs;
    float* out_dist = out;
    float* out_pf   = out + N;
    float* out_ps   = out + 2 * N;
    float* out_pc   = out + 3 * N;
    float* out_mask = out + 6 * N;
    const int tid = blockIdx.x * blockDim.x + threadIdx.x;
    const int stride = gridDim.x * blockDim.x;
    for (int p = tid; p < n_pairs; p += stride) {
        const int pfs = pair_first[p];
        const int pss = pair_second[p];
        const float f0 = (float)shifts[3 * p + 0];
        const float f1 = (float)shifts[3 * p + 1];
        const float f2 = (float)shifts[3 * p + 2];
        const int iaa = real_atoms[pfs];
        const int ibb = real_atoms[pss];
        const float dx = coords[3*ibb+0] - coords[3*iaa+0] + f0*c00 + f1*c10 + f2*c20;
        const float dy = coords[3*ibb+1] - coords[3*iaa+1] + f0*c01 + f1*c11 + f2*c21;
        const float dz = coords[3*ibb+2] - coords[3*iaa+2] + f0*c02 + f1*c12 + f2*c22;
        const float d  = sqrtf(dx*dx + dy*dy + dz*dz);
        const bool  m  = d < HARD_DIST_CUTOFF;
        out_dist[p] = m ? d : 0.0f;
        out_pf[p]   = m ? (float)pfs : -1.0f;
        out_ps[p]   = m ? (float)pss : -1.0f;
        out_pc[3*(size_t)p+0] = m ? dx : 0.0f;
        out_pc[3*(size_t)p+1] = m ? dy : 0.0f;
        out_pc[3*(size_t)p+2] = m ? dz : 0.0f;
        out_mask[p] = m ? 1.0f : 0.0f;
    }
}

extern "C" void kernel_launch(void* const* d_in, const int* in_sizes, int n_in,
                              void* d_out, int out_size, void* d_ws, size_t ws_size,
                              hipStream_t stream) {
    const float* coords      = (const float*)d_in[0];  // (128,1024,3) f32
    const int*   real_atoms  = (const int*)d_in[1];    // (131072,) int
    const int*   shifts      = (const int*)d_in[2];    // (8388608,3) int
    const float* cell        = (const float*)d_in[3];  // (3,3) f32
    const int*   pair_first  = (const int*)d_in[4];    // (8388608,) int
    const int*   pair_second = (const int*)d_in[5];    // (8388608,) int
    float*       out         = (float*)d_out;

    const int n_real  = in_sizes[1];  // 131072
    const int n_pairs = in_sizes[4];  // 8388608

    const size_t tab_bytes = (size_t)n_real * sizeof(f32x4);

    if (ws_size >= tab_bytes && (n_pairs % 1024) == 0) {
        f32x4* tab = (f32x4*)d_ws;
        build_gather_table<<<(n_real + 255) / 256, 256, 0, stream>>>(
            coords, real_atoms, tab, n_real);

        const int grid = n_pairs / 1024;  // 4 pairs/thread, 256 thr/block, exact
        external_neighbors_v6<<<grid, 256, 0, stream>>>(
            tab, shifts, cell, pair_first, pair_second, out, n_pairs);
    } else {
        external_neighbors_v2<<<2048, 256, 0, stream>>>(
            coords, real_atoms, shifts, cell, pair_first, pair_second, out, n_pairs);
    }
}